// Round 1
// baseline (5682.858 us; speedup 1.0000x reference)
//
#include <hip/hip_runtime.h>

// TT-layer: y[b,n1,n2,n3,n4] = sum_{m,r} prod_k core_k * x[b,m1..m4] + bias
// Shapes: x[8192][8][8][8][8] f32; core0[1][8][8][16]; core1[16][8][8][16];
//         core2[16][8][8][16]; core3[16][8][8][1]; bias[8][8][8][8].
// One block per batch element b; loop n1; fused 4-stage contraction in LDS.
// LDS = 16KB(x) + 32KB(t1/t3) + 32KB(t2) = 80KB exactly -> 2 blocks/CU.

__global__ __launch_bounds__(256, 2) void tt_kernel(
    const float* __restrict__ x,
    const float* __restrict__ c0,
    const float* __restrict__ c1,
    const float* __restrict__ c2,
    const float* __restrict__ c3,
    const float* __restrict__ bias,
    float* __restrict__ out)
{
    __shared__ float xs[4096];   // x_b  [m1][m2 m3 m4]
    __shared__ float t13[8192];  // t1 [r1][m2][u(m3m4)] then t3 [n2][n3][r3][m4]
    __shared__ float t2s[8192];  // t2 [n2][r2][u(m3m4)]

    const int b = blockIdx.x;
    const int t = threadIdx.x;

    // ---- load x_b (coalesced float4) ----
    {
        const float4* xg = (const float4*)(x + (size_t)b * 4096);
        float4* xv = (float4*)xs;
        #pragma unroll
        for (int i = 0; i < 4; ++i) xv[t + i * 256] = xg[t + i * 256];
    }
    __syncthreads();

    for (int n1 = 0; n1 < 8; ++n1) {
        // ---- stage 0: t1[r1*512 + j] = sum_m1 c0[(n1*8+m1)*16+r1] * xs[m1*512+j]
        {
            const int r1 = t >> 4;       // 0..15
            const int jg = t & 15;       // j = jg*32 .. +31
            float c0r[8];
            #pragma unroll
            for (int m1 = 0; m1 < 8; ++m1) c0r[m1] = c0[(n1 * 8 + m1) * 16 + r1];
            const float4* xv = (const float4*)xs;
            float4* t1v = (float4*)t13;
            #pragma unroll
            for (int j4 = 0; j4 < 8; ++j4) {
                float4 a = {0.f, 0.f, 0.f, 0.f};
                #pragma unroll
                for (int m1 = 0; m1 < 8; ++m1) {
                    float4 v = xv[m1 * 128 + jg * 8 + j4];
                    a.x += c0r[m1] * v.x; a.y += c0r[m1] * v.y;
                    a.z += c0r[m1] * v.z; a.w += c0r[m1] * v.w;
                }
                t1v[r1 * 128 + jg * 8 + j4] = a;
            }
        }
        __syncthreads();

        // ---- stage 1: t2[n2*1024 + r2*64 + u] =
        //        sum_{r1,m2} c1[((r1*8+n2)*8+m2)*16 + r2] * t1[r1*512 + m2*64 + u]
        {
            const int qg  = t >> 4;            // q = qg*8 + i, q = n2*16 + r2
            const int ug  = t & 15;            // u = ug*4 .. +3
            const int n2  = qg >> 1;
            const int r2b = (qg & 1) * 8;
            float acc[8][4];
            #pragma unroll
            for (int i = 0; i < 8; ++i)
                acc[i][0] = acc[i][1] = acc[i][2] = acc[i][3] = 0.f;
            const float4* t1v = (const float4*)t13;
            #pragma unroll 4
            for (int p = 0; p < 128; ++p) {
                const int r1 = p >> 3, m2 = p & 7;
                const float4* cp = (const float4*)(c1 + (((r1 * 8 + n2) * 8 + m2) * 16 + r2b));
                const float4 ca = cp[0], cb = cp[1];
                const float4 tv = t1v[r1 * 128 + m2 * 16 + ug];
                const float cq[8] = {ca.x, ca.y, ca.z, ca.w, cb.x, cb.y, cb.z, cb.w};
                #pragma unroll
                for (int i = 0; i < 8; ++i) {
                    acc[i][0] += cq[i] * tv.x;
                    acc[i][1] += cq[i] * tv.y;
                    acc[i][2] += cq[i] * tv.z;
                    acc[i][3] += cq[i] * tv.w;
                }
            }
            float4* t2v = (float4*)t2s;
            #pragma unroll
            for (int i = 0; i < 8; ++i)
                t2v[n2 * 256 + (r2b + i) * 16 + ug] =
                    make_float4(acc[i][0], acc[i][1], acc[i][2], acc[i][3]);
        }
        __syncthreads();

        // ---- stage 2: t3[((n2*8+n3)*16+r3)*8 + m4] =
        //        sum_{r2,m3} c2[((r2*8+n3)*8+m3)*16 + r3] * t2[n2*1024 + r2*64 + m3*8 + m4]
        {
            const int qg  = t >> 4;            // q' = qg*8+i, q' = n3*16 + r3
            const int vg  = t & 15;            // n2 = vg>>1, m4 = (vg&1)*4 .. +3
            const int n3  = qg >> 1;
            const int r3b = (qg & 1) * 8;
            const int n2  = vg >> 1;
            const int m4q = vg & 1;            // float4 sub-index of m4
            float acc[8][4];
            #pragma unroll
            for (int i = 0; i < 8; ++i)
                acc[i][0] = acc[i][1] = acc[i][2] = acc[i][3] = 0.f;
            const float4* t2v = (const float4*)t2s;
            #pragma unroll 4
            for (int p = 0; p < 128; ++p) {
                const int r2 = p >> 3, m3 = p & 7;
                const float4* cp = (const float4*)(c2 + (((r2 * 8 + n3) * 8 + m3) * 16 + r3b));
                const float4 ca = cp[0], cb = cp[1];
                const float4 tv = t2v[n2 * 256 + r2 * 16 + m3 * 2 + m4q];
                const float cq[8] = {ca.x, ca.y, ca.z, ca.w, cb.x, cb.y, cb.z, cb.w};
                #pragma unroll
                for (int i = 0; i < 8; ++i) {
                    acc[i][0] += cq[i] * tv.x;
                    acc[i][1] += cq[i] * tv.y;
                    acc[i][2] += cq[i] * tv.z;
                    acc[i][3] += cq[i] * tv.w;
                }
            }
            float4* t3v = (float4*)t13;
            #pragma unroll
            for (int i = 0; i < 8; ++i)
                t3v[((n2 * 8 + n3) * 16 + r3b + i) * 2 + m4q] =
                    make_float4(acc[i][0], acc[i][1], acc[i][2], acc[i][3]);
        }
        __syncthreads();

        // ---- stage 3: y[o=(n2,n3,n4)] = sum_{r3,m4} c3[(r3*8+n4)*8+m4] * t3 + bias
        {
            const int o   = t * 2;
            const int n2  = o >> 6;
            const int n3  = (o >> 3) & 7;
            const int n4a = o & 7;             // even; pair handles n4a, n4a+1
            float a0 = 0.f, a1 = 0.f;
            const float4* t3v = (const float4*)t13;
            #pragma unroll 4
            for (int r3 = 0; r3 < 16; ++r3) {
                const int tb = ((n2 * 8 + n3) * 16 + r3) * 2;
                const float4 ta = t3v[tb], tbv = t3v[tb + 1];
                const float4* pa = (const float4*)(c3 + (r3 * 8 + n4a) * 8);
                const float4 pa0 = pa[0], pa1 = pa[1], pb0 = pa[2], pb1 = pa[3];
                a0 += ta.x * pa0.x + ta.y * pa0.y + ta.z * pa0.z + ta.w * pa0.w
                    + tbv.x * pa1.x + tbv.y * pa1.y + tbv.z * pa1.z + tbv.w * pa1.w;
                a1 += ta.x * pb0.x + ta.y * pb0.y + ta.z * pb0.z + ta.w * pb0.w
                    + tbv.x * pb1.x + tbv.y * pb1.y + tbv.z * pb1.z + tbv.w * pb1.w;
            }
            const int oo = n1 * 512 + o;
            const float2 bv = *(const float2*)(bias + oo);
            float2 res;
            res.x = a0 + bv.x;
            res.y = a1 + bv.y;
            *(float2*)(out + (size_t)b * 4096 + oo) = res;
        }
        __syncthreads();   // protect t13/t2s before next n1 iteration
    }
}

extern "C" void kernel_launch(void* const* d_in, const int* in_sizes, int n_in,
                              void* d_out, int out_size, void* d_ws, size_t ws_size,
                              hipStream_t stream) {
    const float* x    = (const float*)d_in[0];
    const float* c0   = (const float*)d_in[1];
    const float* c1   = (const float*)d_in[2];
    const float* c2   = (const float*)d_in[3];
    const float* c3   = (const float*)d_in[4];
    const float* bias = (const float*)d_in[5];
    float* out = (float*)d_out;
    hipLaunchKernelGGL(tt_kernel, dim3(8192), dim3(256), 0, stream,
                       x, c0, c1, c2, c3, bias, out);
}

// Round 2
// 509.101 us; speedup vs baseline: 11.1625x; 11.1625x over previous
//
#include <hip/hip_runtime.h>

// TT-layer y = (c0 x c1 x c2 x c3) . x + bias, B=8192, all dims 8, ranks 16.
//
// Factorization: precompute (per launch, into d_ws, fp32->bf16):
//   CC [n1][q=(n2*16+r2)][p=(m1*8+m2)]   = sum_r1 c0[n1][m1][r1]*c1[r1][n2][m2][r2]   (8x128x64)
//   C23[row=(n3*8+n4)][s~(r2,m3,m4)]     = sum_r3 c2[r2][n3][m3][r3]*c3[r3][n4][m4]   (64x1024)
// Main kernel, 2 batch elems / block, per n1:
//   stage01: D1[q][(b',u)] = CC_n1 * xt      (M=128,N=128,K=64)  -> scatter to t2t
//   stage2 : y[row][(b',n2)] = C23 * t2t     (M=64, N=16, K=1024) -> +bias -> out
// s-index swizzle: s = (m3*8+m4)*16 + ((r2 + 4*(m3&1)) & 15)  (bank spread; any
// bijection is valid since C23 is precomputed in the same s-order).

typedef __attribute__((ext_vector_type(8))) short bf16x8;
typedef __attribute__((ext_vector_type(4))) float f32x4;

__device__ __forceinline__ short f2bf(float f) {
    union { float f; unsigned u; } v; v.f = f;
    unsigned u = v.u;
    u += 0x7fffu + ((u >> 16) & 1u);   // round-to-nearest-even
    return (short)(u >> 16);
}

// ---------------- precompute kernel: build CC and C23 in d_ws ----------------
__global__ void tt_pre(const float* __restrict__ c0, const float* __restrict__ c1,
                       const float* __restrict__ c2, const float* __restrict__ c3,
                       short* __restrict__ ws) {
    int id = blockIdx.x * 256 + threadIdx.x;     // 0 .. 131071
    if (id < 65536) {
        // CC: id = n1*8192 + q*64 + p
        int p  = id & 63, q = (id >> 6) & 127, n1 = id >> 13;
        int m1 = p >> 3, m2 = p & 7, n2 = q >> 4, r2 = q & 15;
        float s = 0.f;
        #pragma unroll
        for (int r1 = 0; r1 < 16; ++r1)
            s += c0[(n1 * 8 + m1) * 16 + r1] * c1[((r1 * 8 + n2) * 8 + m2) * 16 + r2];
        ws[id] = f2bf(s);
    } else {
        // C23: id2 = row*1024 + s_, row=(n3*8+n4)
        int id2 = id - 65536;
        int s_  = id2 & 1023, row = id2 >> 10;
        int n3 = row >> 3, n4 = row & 7;
        int m3 = s_ >> 7, m4 = (s_ >> 4) & 7, r2s = s_ & 15;
        int r2 = (r2s - 4 * (m3 & 1)) & 15;      // inverse of scatter swizzle
        float s = 0.f;
        #pragma unroll
        for (int r3 = 0; r3 < 16; ++r3)
            s += c2[((r2 * 8 + n3) * 8 + m3) * 16 + r3] * c3[(r3 * 8 + n4) * 8 + m4];
        ws[65536 + id2] = f2bf(s);
    }
}

// ---------------- main kernel ----------------
#define XT_S 72      // xt row stride (shorts): 144B, 16B-aligned, +4 banks/row
#define T2_S 1032    // t2t row stride (shorts): 2064B, 16B-aligned, +4 banks/row

__global__ __launch_bounds__(256, 2) void tt_main(
    const float* __restrict__ x, const short* __restrict__ ws,
    const float* __restrict__ bias, float* __restrict__ out)
{
    __shared__ short xt[128 * XT_S];     // [(b'*64+u)][p]   18432 B
    __shared__ short t2t[16 * T2_S];     // [(b'*8+n2)][s]   33024 B

    const short* cc  = ws;               // [8][128][64]
    const short* c23 = ws + 65536;       // [64][1024]

    const int t = threadIdx.x, w = t >> 6, L = t & 63;
    const int quad = L >> 4, l16 = L & 15;
    const long long b0 = (long long)blockIdx.x * 2;

    // ---- build xt (bf16, transposed): wave w -> b'=w>>1, p-range (w&1)*32..+31, u=L
    {
        const float* xb = x + (b0 + (w >> 1)) * 4096;
        const int pr = (w & 1) * 32;
        short* dst = &xt[(((w >> 1) * 64 + L) * XT_S) + pr];
        #pragma unroll
        for (int g = 0; g < 4; ++g) {
            bf16x8 v;
            #pragma unroll
            for (int j = 0; j < 8; ++j) v[j] = f2bf(xb[(pr + g * 8 + j) * 64 + L]);
            *(bf16x8*)(dst + g * 8) = v;
        }
    }

    // ---- persistent A2 frags (C23): wave w -> rows 16w..16w+15, full K=1024
    bf16x8 a2[32];
    {
        const short* base = c23 + (16 * w + l16) * 1024 + quad * 8;
        #pragma unroll
        for (int kt = 0; kt < 32; ++kt) a2[kt] = *(const bf16x8*)(base + kt * 32);
    }
    __syncthreads();

    // ---- persistent B01 frags (x): wave -> (mh, nh); nh picks b'
    const int mh = w >> 1, nh = w & 1;
    bf16x8 b01[8];                       // [kt*4+nt]
    #pragma unroll
    for (int kt = 0; kt < 2; ++kt)
        #pragma unroll
        for (int nt = 0; nt < 4; ++nt)
            b01[kt * 4 + nt] =
                *(const bf16x8*)&xt[(nh * 64 + nt * 16 + l16) * XT_S + kt * 32 + quad * 8];

    #pragma unroll 1
    for (int n1 = 0; n1 < 8; ++n1) {
        // ======== stage01: D1[q=(n2,r2)][(b',u)] = CC_n1 * xt, M=128 N=128 K=64 ====
        f32x4 acc[4][4] = {};            // [mt][nt]
        #pragma unroll
        for (int kt = 0; kt < 2; ++kt) {
            bf16x8 a1[4];
            const short* ab = cc + n1 * 8192 + (mh * 64 + l16) * 64 + kt * 32 + quad * 8;
            #pragma unroll
            for (int mt = 0; mt < 4; ++mt) a1[mt] = *(const bf16x8*)(ab + mt * 16 * 64);
            #pragma unroll
            for (int mt = 0; mt < 4; ++mt)
                #pragma unroll
                for (int nt = 0; nt < 4; ++nt)
                    acc[mt][nt] = __builtin_amdgcn_mfma_f32_16x16x32_bf16(
                        a1[mt], b01[kt * 4 + nt], acc[mt][nt], 0, 0, 0);
        }
        // ---- scatter D1 -> t2t (b64 stores, swizzled s keeps i=0..3 contiguous)
        #pragma unroll
        for (int mt = 0; mt < 4; ++mt) {
            const int n2 = mh * 4 + mt;
            #pragma unroll
            for (int nt = 0; nt < 4; ++nt) {
                const int u  = nt * 16 + l16;        // 0..63
                const int m3 = u >> 3, m4 = u & 7;
                const int rblk = (quad * 4 + 4 * (m3 & 1)) & 15;
                int2 pk;
                pk.x = (int)((unsigned short)f2bf(acc[mt][nt][0]) |
                             ((unsigned)(unsigned short)f2bf(acc[mt][nt][1]) << 16));
                pk.y = (int)((unsigned short)f2bf(acc[mt][nt][2]) |
                             ((unsigned)(unsigned short)f2bf(acc[mt][nt][3]) << 16));
                *(int2*)&t2t[(nh * 8 + n2) * T2_S + (m3 * 8 + m4) * 16 + rblk] = pk;
            }
        }
        __syncthreads();

        // ======== stage2: y[row=(n3,n4)][(b',n2)] = C23 * t2t, M=64 N=16 K=1024 ====
        f32x4 d0 = {}, d1 = {};
        {
            const short* tb = &t2t[l16 * T2_S + quad * 8];
            #pragma unroll
            for (int kt = 0; kt < 32; kt += 2) {
                bf16x8 bf0 = *(const bf16x8*)(tb + kt * 32);
                bf16x8 bf1 = *(const bf16x8*)(tb + kt * 32 + 32);
                d0 = __builtin_amdgcn_mfma_f32_16x16x32_bf16(a2[kt],     bf0, d0, 0, 0, 0);
                d1 = __builtin_amdgcn_mfma_f32_16x16x32_bf16(a2[kt + 1], bf1, d1, 0, 0, 0);
            }
        }
        // ---- epilogue: rows 16w+quad*4+i, col l16=(b',n2); float4 out+bias
        {
            const int bp = l16 >> 3, n2 = l16 & 7;
            const int off = n1 * 512 + n2 * 64 + 16 * w + quad * 4;
            const float4 bv = *(const float4*)(bias + off);
            float4 ov;
            ov.x = d0[0] + d1[0] + bv.x;
            ov.y = d0[1] + d1[1] + bv.y;
            ov.z = d0[2] + d1[2] + bv.z;
            ov.w = d0[3] + d1[3] + bv.w;
            *(float4*)(out + (b0 + bp) * 4096 + off) = ov;
        }
        __syncthreads();
    }
}

extern "C" void kernel_launch(void* const* d_in, const int* in_sizes, int n_in,
                              void* d_out, int out_size, void* d_ws, size_t ws_size,
                              hipStream_t stream) {
    const float* x    = (const float*)d_in[0];
    const float* c0   = (const float*)d_in[1];
    const float* c1   = (const float*)d_in[2];
    const float* c2   = (const float*)d_in[3];
    const float* c3   = (const float*)d_in[4];
    const float* bias = (const float*)d_in[5];
    float* out = (float*)d_out;
    short* ws  = (short*)d_ws;           // 256 KB used: CC (128K) + C23 (128K)

    hipLaunchKernelGGL(tt_pre, dim3(512), dim3(256), 0, stream, c0, c1, c2, c3, ws);
    hipLaunchKernelGGL(tt_main, dim3(4096), dim3(256), 0, stream, x, ws, bias, out);
}